// Round 6
// baseline (333.046 us; speedup 1.0000x reference)
//
#include <hip/hip_runtime.h>

// DynamicVoxelEncoder: range filter + quantize + scatter-mean per voxel.
// points: [B=4, N=300000, 5] float32 (x,y,z,f0,f1)
// out (flat float32): voxels [B,NV,5] | counts [B,NV] | shape [3]
//
// R6: per-voxel linked lists with 4-byte nodes (next-pointer only; output
// re-reads the points array) + 4-voxel/thread vectorized output pass.
// Fixed, untouchable harness overhead per timed iter: ~148 us ws-poison
// (896 MB fill) + ~37 us out-poison + input restore.

#define NX_ 540
#define NY_ 540
#define NZ_ 8
#define NV_ (NX_ * NY_ * NZ_)
#define B_ 4
#define N_ 300000
#define BN_ (B_ * N_)
#define NVB_ (B_ * NV_)

// ---------------- build: one atomicExch per kept point ----------------

__global__ __launch_bounds__(256) void voxel_build(
    const float* __restrict__ pts,   // [BN_, 5]
    int* __restrict__ head,          // [NVB_], pre-set to -1
    int* __restrict__ nxt)           // [BN_]
{
    int g = blockIdx.x * blockDim.x + threadIdx.x;
    if (g >= BN_) return;

    const float* p = pts + (size_t)g * 5;
    float x = p[0];
    float y = p[1];
    float z = p[2];

    bool keep = (x >= -54.0f) & (x <= 54.0f) &
                (y >= -54.0f) & (y <= 54.0f) &
                (z >= -5.0f)  & (z <= 3.0f);
    if (!keep) return;

    // XLA-canonical quantization: (x - lo) * reciprocal(vox); rcp(0.2f)==5.0f
    int cx = (int)floorf((x + 54.0f) * 5.0f);
    int cy = (int)floorf((y + 54.0f) * 5.0f);
    int cz = (int)floorf(z + 5.0f);
    cx = min(max(cx, 0), NX_ - 1);
    cy = min(max(cy, 0), NY_ - 1);
    cz = min(max(cz, 0), NZ_ - 1);

    int lin = (cz * NY_ + cy) * NX_ + cx;
    int b = g / N_;
    int vox = b * NV_ + lin;

    int old = atomicExch(&head[vox], g);   // previous head (or -1)
    nxt[g] = old;                          // visible to next kernel at k-end
}

// ---------------- output: 4 voxels per thread, vectorized ----------------

__global__ __launch_bounds__(256) void voxel_output4(
    const int* __restrict__ head,    // [NVB_]
    const int* __restrict__ nxt,     // [BN_]
    const float* __restrict__ pts,   // [BN_, 5]
    float* __restrict__ means,       // [NVB_, 5]
    float* __restrict__ cnts,        // [NVB_]
    float* __restrict__ shape_out)   // [3]
{
    int t = blockIdx.x * blockDim.x + threadIdx.x;
    if (t == 0) {
        shape_out[0] = 540.0f;
        shape_out[1] = 540.0f;
        shape_out[2] = 8.0f;
    }
    int v0 = t * 4;
    if (v0 >= NVB_) return;   // NVB_ % 4 == 0, so full quads only

    int4 h4 = *(const int4*)(head + v0);
    int hh[4] = {h4.x, h4.y, h4.z, h4.w};

    float o[20];
    float cf[4];

    #pragma unroll
    for (int j = 0; j < 4; j++) {
        int i = hh[j];
        float s0 = 0.f, s1 = 0.f, s2 = 0.f, s3 = 0.f, s4 = 0.f;
        int c = 0;
        while (i >= 0) {
            const float* p = pts + (size_t)i * 5;
            s0 += p[0]; s1 += p[1]; s2 += p[2]; s3 += p[3]; s4 += p[4];
            c++;
            i = nxt[i];
        }
        float d = (float)max(c, 1);   // sums / max(cnt, 1)
        o[j * 5 + 0] = s0 / d;
        o[j * 5 + 1] = s1 / d;
        o[j * 5 + 2] = s2 / d;
        o[j * 5 + 3] = s3 / d;
        o[j * 5 + 4] = s4 / d;
        cf[j] = (float)c;
    }

    // 4 voxels * 5 floats = 80 B contiguous, 16B-aligned: 5x float4 stores
    float* mb = means + (size_t)v0 * 5;
    #pragma unroll
    for (int k = 0; k < 5; k++) {
        *(float4*)(mb + k * 4) = make_float4(o[k*4+0], o[k*4+1], o[k*4+2], o[k*4+3]);
    }
    *(float4*)(cnts + v0) = make_float4(cf[0], cf[1], cf[2], cf[3]);
}

// ---------------- fallback path (R4, known-good) ----------------

__global__ __launch_bounds__(256) void voxel_scatter(
    const float* __restrict__ pts,
    float* __restrict__ sums,
    float* __restrict__ cnts)
{
    int g = blockIdx.x * blockDim.x + threadIdx.x;
    if (g >= BN_) return;
    const float* p = pts + (size_t)g * 5;
    float x = p[0], y = p[1], z = p[2], f0 = p[3], f1 = p[4];
    bool keep = (x >= -54.0f) & (x <= 54.0f) &
                (y >= -54.0f) & (y <= 54.0f) &
                (z >= -5.0f)  & (z <= 3.0f);
    if (!keep) return;
    int cx = (int)floorf((x + 54.0f) * 5.0f);
    int cy = (int)floorf((y + 54.0f) * 5.0f);
    int cz = (int)floorf(z + 5.0f);
    cx = min(max(cx, 0), NX_ - 1);
    cy = min(max(cy, 0), NY_ - 1);
    cz = min(max(cz, 0), NZ_ - 1);
    int lin = (cz * NY_ + cy) * NX_ + cx;
    int b = g / N_;
    size_t vox = (size_t)b * NV_ + (size_t)lin;
    size_t base = vox * 5;
    atomicAdd(&sums[base + 0], x);
    atomicAdd(&sums[base + 1], y);
    atomicAdd(&sums[base + 2], z);
    atomicAdd(&sums[base + 3], f0);
    atomicAdd(&sums[base + 4], f1);
    atomicAdd(&cnts[vox], 1.0f);
}

__global__ __launch_bounds__(256) void voxel_finalize(
    float* __restrict__ sums,
    const float* __restrict__ cnts,
    float* __restrict__ shape_out)
{
    size_t idx = (size_t)blockIdx.x * blockDim.x + threadIdx.x;
    if (idx == 0) {
        shape_out[0] = 540.0f;
        shape_out[1] = 540.0f;
        shape_out[2] = 8.0f;
    }
    if (idx >= (size_t)NVB_) return;
    float c = cnts[idx];
    if (c > 0.0f) {
        size_t base = idx * 5;
        sums[base + 0] /= c;
        sums[base + 1] /= c;
        sums[base + 2] /= c;
        sums[base + 3] /= c;
        sums[base + 4] /= c;
    }
}

// ---------------- launch ----------------

extern "C" void kernel_launch(void* const* d_in, const int* in_sizes, int n_in,
                              void* d_out, int out_size, void* d_ws, size_t ws_size,
                              hipStream_t stream) {
    const float* points = (const float*)d_in[0];
    float* out = (float*)d_out;

    float* means     = out;                           // [NVB_*5]
    float* cnts      = out + (size_t)NVB_ * 5;        // [NVB_]
    float* shape_out = out + (size_t)NVB_ * 6;        // [3]

    const size_t head_bytes = (size_t)NVB_ * 4;       // 37.3 MB
    const size_t nxt_bytes  = (size_t)BN_ * 4;        // 4.8 MB
    const size_t need = head_bytes + nxt_bytes;       // ~42 MB

    if (ws_size >= need) {
        int* head = (int*)d_ws;
        int* nxt  = (int*)((char*)d_ws + head_bytes);

        // heads -> -1 (0xFF bytes); ws is re-poisoned to 0xAA every launch.
        hipMemsetAsync(head, 0xFF, head_bytes, stream);

        voxel_build<<<(BN_ + 255) / 256, 256, 0, stream>>>(points, head, nxt);

        int threads = NVB_ / 4;
        voxel_output4<<<(threads + 255) / 256, 256, 0, stream>>>(
            head, nxt, points, means, cnts, shape_out);
    } else {
        // fallback: R4 atomic-scatter path (known good)
        hipMemsetAsync(d_out, 0, (size_t)out_size * sizeof(float), stream);
        voxel_scatter<<<(BN_ + 255) / 256, 256, 0, stream>>>(points, means, cnts);
        voxel_finalize<<<(NVB_ + 255) / 256, 256, 0, stream>>>(means, cnts, shape_out);
    }
}